// Round 1
// baseline (441.990 us; speedup 1.0000x reference)
//
#include <hip/hip_runtime.h>
#include <math.h>

#define NUM_BINS 1000
#define MAX_MZ_F 1000.0f
#define B_ROWS 8192
#define N_COLS 2048
#define BLOCK 256

// log1p(exp(-1)) and ln(2) as f32-accurate constants
#define BCE_PE1 0.31326168751822286f
#define BCE_PE0 0.69314718055994531f

__device__ __forceinline__ float wave_reduce_add(float v) {
    #pragma unroll
    for (int off = 32; off > 0; off >>= 1)
        v += __shfl_xor(v, off, 64);
    return v;
}

__global__ __launch_bounds__(BLOCK) void hybrid_loss_main(
    const float* __restrict__ pred_mz,
    const float* __restrict__ pred_in,
    const float* __restrict__ true_mz,
    const float* __restrict__ true_in,
    double* __restrict__ acc)   // acc[0]=cos_sum acc[1]=bce_sum acc[2]=hub_sum acc[3]=cnt_sum
{
    __shared__ float pb[NUM_BINS];
    __shared__ float tb[NUM_BINS];
    __shared__ float xred[4][6];   // 4 waves x 6 partial sums

    const int row = blockIdx.x;
    const int tid = threadIdx.x;

    for (int i = tid; i < NUM_BINS; i += BLOCK) { pb[i] = 0.0f; tb[i] = 0.0f; }
    __syncthreads();

    // ---- binning: vectorized float4 loads, LDS atomic accumulate ----
    {
        const float4* pmz = (const float4*)(pred_mz + (size_t)row * N_COLS);
        const float4* pin = (const float4*)(pred_in + (size_t)row * N_COLS);
        const float4* tmz = (const float4*)(true_mz + (size_t)row * N_COLS);
        const float4* tin = (const float4*)(true_in + (size_t)row * N_COLS);
        const int NV = N_COLS / 4;  // 512 float4 per row
        #pragma unroll 2
        for (int i = tid; i < NV; i += BLOCK) {
            float4 m = pmz[i];
            float4 v = pin[i];
            atomicAdd(&pb[(int)(m.x / MAX_MZ_F * 999.0f)], v.x);
            atomicAdd(&pb[(int)(m.y / MAX_MZ_F * 999.0f)], v.y);
            atomicAdd(&pb[(int)(m.z / MAX_MZ_F * 999.0f)], v.z);
            atomicAdd(&pb[(int)(m.w / MAX_MZ_F * 999.0f)], v.w);
            float4 m2 = tmz[i];
            float4 v2 = tin[i];
            atomicAdd(&tb[(int)(m2.x / MAX_MZ_F * 999.0f)], v2.x);
            atomicAdd(&tb[(int)(m2.y / MAX_MZ_F * 999.0f)], v2.y);
            atomicAdd(&tb[(int)(m2.z / MAX_MZ_F * 999.0f)], v2.z);
            atomicAdd(&tb[(int)(m2.w / MAX_MZ_F * 999.0f)], v2.w);
        }
    }
    __syncthreads();

    // ---- per-bin loss terms ----
    float dot = 0.f, pn2 = 0.f, tn2 = 0.f, bce = 0.f, hub = 0.f, cnt = 0.f;
    for (int i = tid; i < NUM_BINS; i += BLOCK) {
        float p = pb[i];
        float t = tb[i];
        dot += p * t;
        pn2 += p * p;
        tn2 += t * t;
        float te = (t > 0.0f) ? 1.0f : 0.0f;
        bce += (p > 0.0f) ? (1.0f - te + BCE_PE1) : BCE_PE0;
        float d  = p - t;
        float ad = fabsf(d);
        float h  = (ad < 1.0f) ? (0.5f * d * d) : (ad - 0.5f);
        hub += h * te;
        cnt += te;
    }

    // ---- block reduction: wave shuffle, then cross-wave via LDS ----
    dot = wave_reduce_add(dot);
    pn2 = wave_reduce_add(pn2);
    tn2 = wave_reduce_add(tn2);
    bce = wave_reduce_add(bce);
    hub = wave_reduce_add(hub);
    cnt = wave_reduce_add(cnt);

    const int wave = tid >> 6;
    const int lane = tid & 63;
    if (lane == 0) {
        xred[wave][0] = dot; xred[wave][1] = pn2; xred[wave][2] = tn2;
        xred[wave][3] = bce; xred[wave][4] = hub; xred[wave][5] = cnt;
    }
    __syncthreads();

    if (tid == 0) {
        float s0 = 0.f, s1 = 0.f, s2 = 0.f, s3 = 0.f, s4 = 0.f, s5 = 0.f;
        #pragma unroll
        for (int w = 0; w < BLOCK / 64; ++w) {
            s0 += xred[w][0]; s1 += xred[w][1]; s2 += xred[w][2];
            s3 += xred[w][3]; s4 += xred[w][4]; s5 += xred[w][5];
        }
        float pn = fmaxf(sqrtf(s1), 1e-8f);
        float tn = fmaxf(sqrtf(s2), 1e-8f);
        float cosl = 1.0f - s0 / (pn * tn);
        atomicAdd(&acc[0], (double)cosl);
        atomicAdd(&acc[1], (double)s3);
        atomicAdd(&acc[2], (double)s4);
        atomicAdd(&acc[3], (double)s5);
    }
}

__global__ void hybrid_loss_finalize(const double* __restrict__ acc,
                                     float* __restrict__ out)
{
    if (threadIdx.x == 0 && blockIdx.x == 0) {
        double loss_cos  = acc[0] / (double)B_ROWS;
        double loss_peak = acc[1] / ((double)B_ROWS * (double)NUM_BINS);
        double cnt       = acc[3] < 1.0 ? 1.0 : acc[3];
        double loss_int  = acc[2] / cnt;
        out[0] = (float)(0.4 * loss_cos + 0.3 * loss_peak + 0.2 * loss_int);
    }
}

extern "C" void kernel_launch(void* const* d_in, const int* in_sizes, int n_in,
                              void* d_out, int out_size, void* d_ws, size_t ws_size,
                              hipStream_t stream) {
    const float* pred_mz = (const float*)d_in[0];
    const float* pred_in = (const float*)d_in[1];
    const float* true_mz = (const float*)d_in[2];
    const float* true_in = (const float*)d_in[3];
    double* acc = (double*)d_ws;
    float* out = (float*)d_out;

    hipMemsetAsync(acc, 0, 4 * sizeof(double), stream);
    hybrid_loss_main<<<B_ROWS, BLOCK, 0, stream>>>(pred_mz, pred_in, true_mz, true_in, acc);
    hybrid_loss_finalize<<<1, 64, 0, stream>>>(acc, out);
}

// Round 2
// 203.400 us; speedup vs baseline: 2.1730x; 2.1730x over previous
//
#include <hip/hip_runtime.h>
#include <math.h>

#define NUM_BINS 1000
#define MAX_MZ_F 1000.0f
#define B_ROWS 8192
#define N_COLS 2048
#define BLOCK 256

// log1p(exp(-1)) and ln(2) as f32-accurate constants
#define BCE_PE1 0.31326168751822286f
#define BCE_PE0 0.69314718055994531f

__device__ __forceinline__ float wave_reduce_add(float v) {
    #pragma unroll
    for (int off = 32; off > 0; off >>= 1)
        v += __shfl_xor(v, off, 64);
    return v;
}

__global__ __launch_bounds__(BLOCK) void hybrid_loss_main(
    const float* __restrict__ pred_mz,
    const float* __restrict__ pred_in,
    const float* __restrict__ true_mz,
    const float* __restrict__ true_in,
    float4* __restrict__ part)   // part[row] = {cosl, bce, hub, cnt}
{
    __shared__ float pb[NUM_BINS];
    __shared__ float tb[NUM_BINS];
    __shared__ float xred[4][6];   // 4 waves x 6 partial sums

    const int row = blockIdx.x;
    const int tid = threadIdx.x;

    for (int i = tid; i < NUM_BINS; i += BLOCK) { pb[i] = 0.0f; tb[i] = 0.0f; }
    __syncthreads();

    // ---- binning: vectorized float4 loads, LDS atomic accumulate ----
    {
        const float4* pmz = (const float4*)(pred_mz + (size_t)row * N_COLS);
        const float4* pin = (const float4*)(pred_in + (size_t)row * N_COLS);
        const float4* tmz = (const float4*)(true_mz + (size_t)row * N_COLS);
        const float4* tin = (const float4*)(true_in + (size_t)row * N_COLS);
        const int NV = N_COLS / 4;  // 512 float4 per row
        #pragma unroll 2
        for (int i = tid; i < NV; i += BLOCK) {
            float4 m = pmz[i];
            float4 v = pin[i];
            atomicAdd(&pb[(int)(m.x / MAX_MZ_F * 999.0f)], v.x);
            atomicAdd(&pb[(int)(m.y / MAX_MZ_F * 999.0f)], v.y);
            atomicAdd(&pb[(int)(m.z / MAX_MZ_F * 999.0f)], v.z);
            atomicAdd(&pb[(int)(m.w / MAX_MZ_F * 999.0f)], v.w);
            float4 m2 = tmz[i];
            float4 v2 = tin[i];
            atomicAdd(&tb[(int)(m2.x / MAX_MZ_F * 999.0f)], v2.x);
            atomicAdd(&tb[(int)(m2.y / MAX_MZ_F * 999.0f)], v2.y);
            atomicAdd(&tb[(int)(m2.z / MAX_MZ_F * 999.0f)], v2.z);
            atomicAdd(&tb[(int)(m2.w / MAX_MZ_F * 999.0f)], v2.w);
        }
    }
    __syncthreads();

    // ---- per-bin loss terms ----
    float dot = 0.f, pn2 = 0.f, tn2 = 0.f, bce = 0.f, hub = 0.f, cnt = 0.f;
    for (int i = tid; i < NUM_BINS; i += BLOCK) {
        float p = pb[i];
        float t = tb[i];
        dot += p * t;
        pn2 += p * p;
        tn2 += t * t;
        float te = (t > 0.0f) ? 1.0f : 0.0f;
        bce += (p > 0.0f) ? (1.0f - te + BCE_PE1) : BCE_PE0;
        float d  = p - t;
        float ad = fabsf(d);
        float h  = (ad < 1.0f) ? (0.5f * d * d) : (ad - 0.5f);
        hub += h * te;
        cnt += te;
    }

    // ---- block reduction: wave shuffle, then cross-wave via LDS ----
    dot = wave_reduce_add(dot);
    pn2 = wave_reduce_add(pn2);
    tn2 = wave_reduce_add(tn2);
    bce = wave_reduce_add(bce);
    hub = wave_reduce_add(hub);
    cnt = wave_reduce_add(cnt);

    const int wave = tid >> 6;
    const int lane = tid & 63;
    if (lane == 0) {
        xred[wave][0] = dot; xred[wave][1] = pn2; xred[wave][2] = tn2;
        xred[wave][3] = bce; xred[wave][4] = hub; xred[wave][5] = cnt;
    }
    __syncthreads();

    if (tid == 0) {
        float s0 = 0.f, s1 = 0.f, s2 = 0.f, s3 = 0.f, s4 = 0.f, s5 = 0.f;
        #pragma unroll
        for (int w = 0; w < BLOCK / 64; ++w) {
            s0 += xred[w][0]; s1 += xred[w][1]; s2 += xred[w][2];
            s3 += xred[w][3]; s4 += xred[w][4]; s5 += xred[w][5];
        }
        float pn = fmaxf(sqrtf(s1), 1e-8f);
        float tn = fmaxf(sqrtf(s2), 1e-8f);
        float cosl = 1.0f - s0 / (pn * tn);
        float4 r;
        r.x = cosl; r.y = s3; r.z = s4; r.w = s5;
        part[row] = r;
    }
}

__global__ __launch_bounds__(256) void hybrid_loss_reduce(
    const float4* __restrict__ part,
    float* __restrict__ out)
{
    __shared__ double xr[4][4];
    const int tid = threadIdx.x;

    double c = 0.0, b = 0.0, h = 0.0, n = 0.0;
    for (int i = tid; i < B_ROWS; i += 256) {
        float4 v = part[i];
        c += (double)v.x; b += (double)v.y; h += (double)v.z; n += (double)v.w;
    }
    #pragma unroll
    for (int off = 32; off > 0; off >>= 1) {
        c += __shfl_xor(c, off, 64);
        b += __shfl_xor(b, off, 64);
        h += __shfl_xor(h, off, 64);
        n += __shfl_xor(n, off, 64);
    }
    const int wave = tid >> 6;
    const int lane = tid & 63;
    if (lane == 0) { xr[wave][0] = c; xr[wave][1] = b; xr[wave][2] = h; xr[wave][3] = n; }
    __syncthreads();

    if (tid == 0) {
        double C = 0.0, Bs = 0.0, H = 0.0, Nn = 0.0;
        #pragma unroll
        for (int w = 0; w < 4; ++w) {
            C += xr[w][0]; Bs += xr[w][1]; H += xr[w][2]; Nn += xr[w][3];
        }
        double loss_cos  = C / (double)B_ROWS;
        double loss_peak = Bs / ((double)B_ROWS * (double)NUM_BINS);
        double cnt       = Nn < 1.0 ? 1.0 : Nn;
        double loss_int  = H / cnt;
        out[0] = (float)(0.4 * loss_cos + 0.3 * loss_peak + 0.2 * loss_int);
    }
}

extern "C" void kernel_launch(void* const* d_in, const int* in_sizes, int n_in,
                              void* d_out, int out_size, void* d_ws, size_t ws_size,
                              hipStream_t stream) {
    const float* pred_mz = (const float*)d_in[0];
    const float* pred_in = (const float*)d_in[1];
    const float* true_mz = (const float*)d_in[2];
    const float* true_in = (const float*)d_in[3];
    float4* part = (float4*)d_ws;   // 8192 * 16 B = 128 KiB
    float* out = (float*)d_out;

    hybrid_loss_main<<<B_ROWS, BLOCK, 0, stream>>>(pred_mz, pred_in, true_mz, true_in, part);
    hybrid_loss_reduce<<<1, 256, 0, stream>>>(part, out);
}